// Round 6
// baseline (291.052 us; speedup 1.0000x reference)
//
#include <hip/hip_runtime.h>
#include <hip/hip_cooperative_groups.h>
#include <stdint.h>

namespace cg = cooperative_groups;

#define E2V     600000
#define NNODES  50000
#define UCNT    500
#define DE      100
#define DOUT    100
#define NB      16
#define KTOT    3328      // 3200 (G) + 100 (x/root) + 1 (bias) + 27 pad
#define KCH     104       // KTOT/32
#define CAP2    128       // per-slot edge list capacity (expected ~12)
#define MROWS   512
#define GRID    512
#define TTOT    (GRID*256)

using short8 = __attribute__((ext_vector_type(8))) short;
using f32x4  = __attribute__((ext_vector_type(4))) float;

static constexpr size_t align256(size_t x){ return (x + 255) & ~size_t(255); }
static constexpr size_t OFF_OVR  = 0;                                        // 50000 i32
static constexpr size_t OFF_IHEA = align256(OFF_OVR + (size_t)NNODES*4);     // 512 i32
static constexpr size_t OFF_INEX = OFF_IHEA + MROWS*4;                       // 512 i32
static constexpr size_t OFF_SCNT = OFF_INEX + MROWS*4;                       // 512 i32
static constexpr size_t OFF_EL2  = align256(OFF_SCNT + MROWS*4);             // 512*128 i32
static constexpr size_t OFF_GM   = align256(OFF_EL2 + (size_t)MROWS*CAP2*4); // 512*3328 bf16
static constexpr size_t OFF_GS   = OFF_GM + (size_t)MROWS*KTOT*2;
static constexpr size_t OFF_BTM  = align256(OFF_GS + (size_t)MROWS*KTOT*2);  // 100*3328 bf16
static constexpr size_t OFF_BTS  = OFF_BTM + (size_t)DOUT*KTOT*2;            // total ~8 MB

#define TR_BLOCKS  (KCH * 4 * 2)     // 832 transpose tiles

__device__ __forceinline__ unsigned short f2b(float f){
    uint32_t u = __float_as_uint(f);
    uint32_t r = (u + 0x7FFFu + ((u >> 16) & 1u)) >> 16;
    return (unsigned short)r;
}

__device__ __forceinline__ float bt_src(const float* __restrict__ basis,
                                        const float* __restrict__ root,
                                        const float* __restrict__ bias,
                                        int k, int j){
    if (j >= 100) return 0.f;
    if (k < 3200) return basis[k*100 + j];
    if (k < 3300) return root[(k-3200)*100 + j];
    if (k == 3300) return bias[j];
    return 0.f;
}

__global__ __launch_bounds__(256) void k_fused(
        const float* __restrict__ ent, const float* __restrict__ rel,
        const float* __restrict__ unseen,
        const float* __restrict__ am, const float* __restrict__ as_,
        const float* __restrict__ bm, const float* __restrict__ bs,
        const float* __restrict__ rm, const float* __restrict__ rs,
        const float* __restrict__ qm, const float* __restrict__ qs,
        const int* __restrict__ node_id, const int* __restrict__ eidx,
        const int* __restrict__ etype, const int* __restrict__ rel_index,
        const int* __restrict__ unseen_index,
        int* __restrict__ ovr, int* __restrict__ ihead, int* __restrict__ inext,
        int* __restrict__ scnt, int* __restrict__ elist,
        unsigned short* __restrict__ Gm, unsigned short* __restrict__ Gs,
        unsigned short* __restrict__ Btm, unsigned short* __restrict__ Bts,
        float* __restrict__ out){
    cg::grid_group gg = cg::this_grid();
    int bx = blockIdx.x, tid = threadIdx.x;
    int gtid = bx*256 + tid;

    __shared__ float tile[32][33];
    __shared__ __align__(16) float sM[8][200];
    __shared__ __align__(16) float sAm[8][16], sAs[8][16];
    __shared__ const float* sPX[8];
    __shared__ const float* sPR[8];
    __shared__ int sT[8];

    // ---- P0: init ovr/ihead/scnt + B_aug^T transpose (bf16 [j][k]) ----
    if (gtid < NNODES) ovr[gtid] = -1;
    if (gtid < MROWS){ ihead[gtid] = -1; scnt[gtid] = 0; }
    for (int t = bx; t < TR_BLOCKS; t += GRID){
        int kt = t % KCH, jt = (t / KCH) & 3, br = t / (KCH*4);
        const float* basis = br ? bs : bm;
        const float* root  = br ? rs : rm;
        const float* bias  = br ? qs : qm;
        unsigned short* bt = br ? Bts : Btm;
        int k0 = kt*32, j0 = jt*32;
        int tx = tid & 31, ty = tid >> 5;
        __syncthreads();
        for (int r = ty; r < 32; r += 8)
            tile[r][tx] = bt_src(basis, root, bias, k0 + r, j0 + tx);
        __syncthreads();
        for (int r = ty; r < 32; r += 8){
            int j = j0 + r;
            if (j < 100) bt[(size_t)j*KTOT + k0 + tx] = f2b(tile[tx][r]);
        }
    }
    gg.sync();

    // ---- P1: scatter unseen positions (last-wins) ----
    if (gtid < UCNT) atomicMax(&ovr[unseen_index[gtid]], gtid);
    gg.sync();

    // ---- P2: inverse chains + edge filter -> per-slot lists ----
    if (gtid < UCNT){
        int slot = ovr[unseen_index[gtid]];
        inext[gtid] = atomicExch(&ihead[slot], gtid);
    }
    for (int e = gtid; e < E2V; e += TTOT){
        int slot = ovr[eidx[E2V + e]];
        if (slot >= 0){
            int pos = atomicAdd(&scnt[slot], 1);
            if (pos < CAP2) elist[slot * CAP2 + pos] = e;
        }
    }
    gg.sync();

    // ---- P3: build G row for slot = bx ----
    {
        int slot = bx;
        int nT = (slot < UCNT) ? scnt[slot] : 0;
        int nE = nT > CAP2 ? CAP2 : nT;
        float gm[16], gs[16];
        #pragma unroll
        for (int b = 0; b < NB; ++b){ gm[b] = 0.f; gs[b] = 0.f; }
        for (int c0 = 0; c0 < nE; c0 += 8){
            int kc = nE - c0; if (kc > 8) kc = 8;
            if (tid < kc){
                int e = elist[slot*CAP2 + c0 + tid];
                sT[tid] = etype[e];
                int s = eidx[e];
                int p = ovr[s];
                sPX[tid] = (p >= 0) ? unseen + (size_t)p*DE : ent + (size_t)node_id[s]*DE;
                sPR[tid] = rel + (size_t)rel_index[e]*DE;
            }
            __syncthreads();
            for (int q = tid; q < kc*50; q += 256){
                int eL = q / 50, s = q % 50;
                const float* base = (s < 25) ? sPX[eL] : sPR[eL];
                int off = (s < 25) ? s*4 : (s-25)*4;
                float4 v = *(const float4*)(base + off);
                int kb = (s < 25) ? s*4 : (s-25)*4 + 100;
                *(float4*)&sM[eL][kb] = v;
            }
            if (tid < kc*16){
                int eL = tid >> 4, b = tid & 15;
                int t = sT[eL];
                sAm[eL][b] = am[t*NB + b];
                sAs[eL][b] = as_[t*NB + b];
            }
            __syncthreads();
            if (tid < 200){
                for (int e = 0; e < kc; ++e){
                    float mk = sM[e][tid];
                    const float4* pa = (const float4*)&sAm[e][0];
                    const float4* ps = (const float4*)&sAs[e][0];
                    #pragma unroll
                    for (int q = 0; q < 4; ++q){
                        float4 va = pa[q], vs = ps[q];
                        gm[q*4+0] += va.x*mk; gm[q*4+1] += va.y*mk;
                        gm[q*4+2] += va.z*mk; gm[q*4+3] += va.w*mk;
                        gs[q*4+0] += vs.x*mk; gs[q*4+1] += vs.y*mk;
                        gs[q*4+2] += vs.z*mk; gs[q*4+3] += vs.w*mk;
                    }
                }
            }
            __syncthreads();
        }
        size_t row = (size_t)slot * KTOT;
        float inv = 1.f / fmaxf((float)nT, 1.f);
        if (tid < 200){
            #pragma unroll
            for (int b = 0; b < NB; ++b){
                Gm[row + b*200 + tid] = f2b(gm[b] * inv);
                Gs[row + b*200 + tid] = f2b(gs[b] * inv);
            }
        }
        if (tid < 100){
            float xv = (slot < UCNT) ? unseen[(size_t)slot*DE + tid] : 0.f;
            unsigned short h = f2b(xv);
            Gm[row + 3200 + tid] = h; Gs[row + 3200 + tid] = h;
        } else if (tid == 100){
            Gm[row + 3300] = f2b(1.f); Gs[row + 3300] = f2b(1.f);
        } else if (tid > 100 && tid < 128){
            Gm[row + 3200 + tid] = 0; Gs[row + 3200 + tid] = 0;   // 3301..3327
        }
    }
    gg.sync();

    // ---- P4: out = G_aug @ B_aug (MFMA), direct scatter to the 3 output blocks ----
    {
        int wid = bx*4 + (tid >> 6);       // 0..2047, jobs 0..447
        if (wid < 448){
            int lane = tid & 63;
            int br = wid / 224;
            int w2 = wid % 224;
            int m16 = w2 & 31;
            int jt  = w2 >> 5;
            const unsigned short* A  = br ? Gs : Gm;
            const unsigned short* Bt = br ? Bts : Btm;
            int rowa = lane & 15, ko = (lane >> 4) * 8;
            int j0 = (jt == 6) ? 84 : jt*16;          // overlap trick, guard col>=96
            int col = j0 + rowa;
            const unsigned short* ap = A  + (size_t)(m16*16 + rowa)*KTOT + ko;
            const unsigned short* bp = Bt + (size_t)col*KTOT + ko;
            f32x4 acc = {0.f, 0.f, 0.f, 0.f};
            #pragma unroll 8
            for (int kc = 0; kc < KCH; ++kc){
                short8 av = *(const short8*)(ap + kc*32);
                short8 bv = *(const short8*)(bp + kc*32);
                acc = __builtin_amdgcn_mfma_f32_16x16x32_bf16(av, bv, acc, 0, 0, 0);
            }
            if (jt < 6 || col >= 96){
                int r0 = m16*16 + (lane >> 4)*4;
                #pragma unroll
                for (int r = 0; r < 4; ++r){
                    int u = ihead[r0 + r];
                    while (u >= 0){
                        if (br == 0){
                            out[(size_t)u*100 + col] = acc[r];
                            out[(size_t)(UCNT + u)*100 + col] = acc[r];
                        } else {
                            out[(size_t)(2*UCNT + u)*100 + col] = acc[r];
                        }
                        u = inext[u];
                    }
                }
            }
        }
    }
}

extern "C" void kernel_launch(void* const* d_in, const int* in_sizes, int n_in,
                              void* d_out, int out_size, void* d_ws, size_t ws_size,
                              hipStream_t stream){
    const float* ent        = (const float*)d_in[0];
    const float* rel_table  = (const float*)d_in[1];
    const float* unseen_emb = (const float*)d_in[2];
    const float* att_mu     = (const float*)d_in[3];
    const float* basis_mu   = (const float*)d_in[4];
    const float* root_mu    = (const float*)d_in[5];
    const float* bias_mu    = (const float*)d_in[6];
    const float* att_sig    = (const float*)d_in[7];
    const float* basis_sig  = (const float*)d_in[8];
    const float* root_sig   = (const float*)d_in[9];
    const float* bias_sig   = (const float*)d_in[10];
    const int* node_id      = (const int*)d_in[11];
    const int* edge_index   = (const int*)d_in[12];
    const int* edge_type    = (const int*)d_in[13];
    const int* rel_index    = (const int*)d_in[14];
    const int* unseen_index = (const int*)d_in[15];
    float* out = (float*)d_out;
    char* ws = (char*)d_ws;

    int* ovr   = (int*)(ws + OFF_OVR);
    int* ihead = (int*)(ws + OFF_IHEA);
    int* inext = (int*)(ws + OFF_INEX);
    int* scnt  = (int*)(ws + OFF_SCNT);
    int* elist = (int*)(ws + OFF_EL2);
    unsigned short* Gm  = (unsigned short*)(ws + OFF_GM);
    unsigned short* Gs  = (unsigned short*)(ws + OFF_GS);
    unsigned short* Btm = (unsigned short*)(ws + OFF_BTM);
    unsigned short* Bts = (unsigned short*)(ws + OFF_BTS);

    void* kargs[] = {
        (void*)&ent, (void*)&rel_table, (void*)&unseen_emb,
        (void*)&att_mu, (void*)&att_sig,
        (void*)&basis_mu, (void*)&basis_sig,
        (void*)&root_mu, (void*)&root_sig,
        (void*)&bias_mu, (void*)&bias_sig,
        (void*)&node_id, (void*)&edge_index, (void*)&edge_type,
        (void*)&rel_index, (void*)&unseen_index,
        (void*)&ovr, (void*)&ihead, (void*)&inext, (void*)&scnt, (void*)&elist,
        (void*)&Gm, (void*)&Gs, (void*)&Btm, (void*)&Bts, (void*)&out
    };
    hipLaunchCooperativeKernel((const void*)k_fused, dim3(GRID), dim3(256),
                               kargs, 0, stream);
}

// Round 7
// 58.260 us; speedup vs baseline: 4.9957x; 4.9957x over previous
//
#include <hip/hip_runtime.h>
#include <stdint.h>

#define E2V     600000
#define NNODES  50000
#define UCNT    500
#define DE      100
#define DOUT    100
#define NB      16
#define KTOT    3328      // 3200 (G) + 100 (x/root) + 1 (bias) + 27 pad
#define KCH     104       // KTOT/32
#define CAP2    128       // per-slot edge list capacity (expected ~12)
#define MROWS   512

using short8 = __attribute__((ext_vector_type(8))) short;
using f32x4  = __attribute__((ext_vector_type(4))) float;

static constexpr size_t align256(size_t x){ return (x + 255) & ~size_t(255); }
static constexpr size_t OFF_OVR  = 0;                                        // 50000 i32
static constexpr size_t OFF_IHEA = align256(OFF_OVR + (size_t)NNODES*4);     // 512 i32
static constexpr size_t OFF_INEX = OFF_IHEA + MROWS*4;                       // 512 i32
static constexpr size_t OFF_SCNT = OFF_INEX + MROWS*4;                       // 512 i32
static constexpr size_t OFF_EL2  = align256(OFF_SCNT + MROWS*4);             // 512*128 i32
static constexpr size_t OFF_GM   = align256(OFF_EL2 + (size_t)MROWS*CAP2*4); // 512*3328 bf16
static constexpr size_t OFF_GS   = OFF_GM + (size_t)MROWS*KTOT*2;
static constexpr size_t OFF_BTM  = align256(OFF_GS + (size_t)MROWS*KTOT*2);  // 100*3328 bf16
static constexpr size_t OFF_BTS  = OFF_BTM + (size_t)DOUT*KTOT*2;            // total ~8 MB

#define TR_BLOCKS 832     // KCH * 4 j-tiles * 2 branches

__device__ __forceinline__ unsigned short f2b(float f){
    uint32_t u = __float_as_uint(f);
    uint32_t r = (u + 0x7FFFu + ((u >> 16) & 1u)) >> 16;
    return (unsigned short)r;
}

__device__ __forceinline__ float bt_src(const float* __restrict__ basis,
                                        const float* __restrict__ root,
                                        const float* __restrict__ bias,
                                        int k, int j){
    if (j >= 100) return 0.f;
    if (k < 3200) return basis[k*100 + j];
    if (k < 3300) return root[(k-3200)*100 + j];
    if (k == 3300) return bias[j];
    return 0.f;
}

// ---- K1: blocks 0..831: init(ovr/ihead/scnt, device-scope) + B_aug^T transpose.
//          block 832: verify-spin on its inputs, then scatter + inverse chains. ----
__global__ __launch_bounds__(256) void k_setup(
        const int* __restrict__ unseen_index,
        int* __restrict__ ovr, int* __restrict__ ihead, int* __restrict__ inext,
        int* __restrict__ scnt,
        const float* __restrict__ bm, const float* __restrict__ bs,
        const float* __restrict__ rm, const float* __restrict__ rs,
        const float* __restrict__ qm, const float* __restrict__ qs,
        unsigned short* __restrict__ btm, unsigned short* __restrict__ bts){
    int bx = blockIdx.x, tid = threadIdx.x;
    if (bx < TR_BLOCKS){
        int gtid = bx*256 + tid;
        if (gtid < NNODES)
            __hip_atomic_store(&ovr[gtid], -1, __ATOMIC_RELAXED, __HIP_MEMORY_SCOPE_AGENT);
        if (gtid < MROWS){
            __hip_atomic_store(&ihead[gtid], -1, __ATOMIC_RELAXED, __HIP_MEMORY_SCOPE_AGENT);
            scnt[gtid] = 0;
        }
        // transpose tile bx -> B_aug^T [j][k] bf16
        int kt = bx % KCH, jt = (bx / KCH) & 3, br = bx / (KCH*4);
        const float* basis = br ? bs : bm;
        const float* root  = br ? rs : rm;
        const float* bias  = br ? qs : qm;
        unsigned short* bt = br ? bts : btm;
        int k0 = kt*32, j0 = jt*32;
        __shared__ float tile[32][33];
        int tx = tid & 31, ty = tid >> 5;
        for (int r = ty; r < 32; r += 8)
            tile[r][tx] = bt_src(basis, root, bias, k0 + r, j0 + tx);
        __syncthreads();
        for (int r = ty; r < 32; r += 8){
            int j = j0 + r;
            if (j < 100) bt[(size_t)j*KTOT + k0 + tx] = f2b(tile[tx][r]);
        }
        return;
    }
    // ---- spinner block (launched last): wait for exactly the entries it uses ----
    for (int u = tid; u < UCNT; u += 256){
        int n = unseen_index[u];
        while (__hip_atomic_load(&ovr[n], __ATOMIC_RELAXED, __HIP_MEMORY_SCOPE_AGENT) != -1){}
    }
    for (int i = tid; i < MROWS; i += 256){
        while (__hip_atomic_load(&ihead[i], __ATOMIC_RELAXED, __HIP_MEMORY_SCOPE_AGENT) != -1){}
    }
    __syncthreads();
    // scatter (last-wins via atomicMax)
    for (int u = tid; u < UCNT; u += 256)
        atomicMax(&ovr[unseen_index[u]], u);
    __syncthreads();
    // inverse chains: slot -> list of u
    for (int u = tid; u < UCNT; u += 256){
        int slot = __hip_atomic_load(&ovr[unseen_index[u]], __ATOMIC_RELAXED,
                                     __HIP_MEMORY_SCOPE_AGENT);
        inext[u] = atomicExch(&ihead[slot], u);
    }
}

// ---- K2: filter edges with unseen dst -> per-slot lists (int4-vectorized dst) ----
__global__ __launch_bounds__(256) void k_filter(
        const int* __restrict__ eidx, const int* __restrict__ ovr,
        int* __restrict__ scnt, int* __restrict__ elist){
    int i = threadIdx.x + blockIdx.x * 256;          // 150000 int4 jobs
    if (i >= E2V/4) return;
    int4 d = *(const int4*)(eidx + E2V + i*4);
    int e0 = i*4;
    int s0 = ovr[d.x], s1 = ovr[d.y], s2 = ovr[d.z], s3 = ovr[d.w];
    if (s0 >= 0){ int p = atomicAdd(&scnt[s0],1); if (p < CAP2) elist[s0*CAP2+p] = e0;   }
    if (s1 >= 0){ int p = atomicAdd(&scnt[s1],1); if (p < CAP2) elist[s1*CAP2+p] = e0+1; }
    if (s2 >= 0){ int p = atomicAdd(&scnt[s2],1); if (p < CAP2) elist[s2*CAP2+p] = e0+2; }
    if (s3 >= 0){ int p = atomicAdd(&scnt[s3],1); if (p < CAP2) elist[s3*CAP2+p] = e0+3; }
}

// ---- K3: build G rows: G[slot] = [ (1/cnt)*sum_e att[t_e]⊗m_e | x | 1 | 0 ] bf16 ----
__global__ __launch_bounds__(256) void k_g(
        const int* __restrict__ scnt, const int* __restrict__ elist,
        const int* __restrict__ ovr, const int* __restrict__ eidx,
        const int* __restrict__ etype, const int* __restrict__ rel_index,
        const int* __restrict__ node_id,
        const float* __restrict__ ent, const float* __restrict__ unseen,
        const float* __restrict__ rel,
        const float* __restrict__ am, const float* __restrict__ as_,
        unsigned short* __restrict__ Gm, unsigned short* __restrict__ Gs){
    int slot = blockIdx.x;
    int tid  = threadIdx.x;
    int nT = (slot < UCNT) ? scnt[slot] : 0;
    int nE = nT > CAP2 ? CAP2 : nT;
    __shared__ __align__(16) float sM[8][200];
    __shared__ __align__(16) float sAm[8][16], sAs[8][16];
    __shared__ const float* sPX[8];
    __shared__ const float* sPR[8];
    __shared__ int sT[8];
    float gm[16], gs[16];
    #pragma unroll
    for (int b = 0; b < NB; ++b){ gm[b] = 0.f; gs[b] = 0.f; }

    for (int c0 = 0; c0 < nE; c0 += 8){
        int kc = nE - c0; if (kc > 8) kc = 8;
        if (tid < kc){
            int e = elist[slot*CAP2 + c0 + tid];
            sT[tid] = etype[e];
            int s = eidx[e];
            int p = ovr[s];
            sPX[tid] = (p >= 0) ? unseen + (size_t)p*DE : ent + (size_t)node_id[s]*DE;
            sPR[tid] = rel + (size_t)rel_index[e]*DE;
        }
        __syncthreads();
        for (int q = tid; q < kc*50; q += 256){
            int eL = q / 50, s = q % 50;
            const float* base = (s < 25) ? sPX[eL] : sPR[eL];
            int off = (s < 25) ? s*4 : (s-25)*4;
            float4 v = *(const float4*)(base + off);
            int kb = (s < 25) ? s*4 : (s-25)*4 + 100;
            *(float4*)&sM[eL][kb] = v;
        }
        if (tid < kc*16){
            int eL = tid >> 4, b = tid & 15;
            int t = sT[eL];
            sAm[eL][b] = am[t*NB + b];
            sAs[eL][b] = as_[t*NB + b];
        }
        __syncthreads();
        if (tid < 200){
            for (int e = 0; e < kc; ++e){
                float mk = sM[e][tid];
                const float4* pa = (const float4*)&sAm[e][0];
                const float4* ps = (const float4*)&sAs[e][0];
                #pragma unroll
                for (int q = 0; q < 4; ++q){
                    float4 va = pa[q], vs = ps[q];
                    gm[q*4+0] += va.x*mk; gm[q*4+1] += va.y*mk;
                    gm[q*4+2] += va.z*mk; gm[q*4+3] += va.w*mk;
                    gs[q*4+0] += vs.x*mk; gs[q*4+1] += vs.y*mk;
                    gs[q*4+2] += vs.z*mk; gs[q*4+3] += vs.w*mk;
                }
            }
        }
        __syncthreads();
    }
    size_t row = (size_t)slot * KTOT;
    float inv = 1.f / fmaxf((float)nT, 1.f);
    if (tid < 200){
        #pragma unroll
        for (int b = 0; b < NB; ++b){
            Gm[row + b*200 + tid] = f2b(gm[b] * inv);
            Gs[row + b*200 + tid] = f2b(gs[b] * inv);
        }
    }
    if (tid < 100){
        float xv = (slot < UCNT) ? unseen[(size_t)slot*DE + tid] : 0.f;
        unsigned short h = f2b(xv);
        Gm[row + 3200 + tid] = h; Gs[row + 3200 + tid] = h;
    } else if (tid == 100){
        Gm[row + 3300] = f2b(1.f); Gs[row + 3300] = f2b(1.f);
    } else if (tid > 100 && tid < 128){
        Gm[row + 3200 + tid] = 0; Gs[row + 3200 + tid] = 0;   // 3301..3327
    }
}

// ---- K4: out = G_aug @ B_aug (bf16 MFMA), direct scatter to the 3 output blocks ----
__global__ __launch_bounds__(256) void k_gemm(
        const unsigned short* __restrict__ Gm, const unsigned short* __restrict__ Gs,
        const unsigned short* __restrict__ Btm, const unsigned short* __restrict__ Bts,
        const int* __restrict__ ihead, const int* __restrict__ inext,
        float* __restrict__ out){
    int wid = blockIdx.x * 4 + (threadIdx.x >> 6);     // 0..447
    int lane = threadIdx.x & 63;
    int br = wid / 224;
    int w2 = wid % 224;
    int m16 = w2 & 31;                                  // 32 M-tiles of 16 rows
    int jt  = w2 >> 5;                                  // 7 j-tiles
    const unsigned short* A  = br ? Gs : Gm;
    const unsigned short* Bt = br ? Bts : Btm;
    int rowa = lane & 15, ko = (lane >> 4) * 8;
    int j0 = (jt == 6) ? 84 : jt*16;                    // overlap trick, guard col>=96
    int col = j0 + rowa;
    const unsigned short* ap = A  + (size_t)(m16*16 + rowa)*KTOT + ko;
    const unsigned short* bp = Bt + (size_t)col*KTOT + ko;
    f32x4 acc = {0.f, 0.f, 0.f, 0.f};
    #pragma unroll 8
    for (int kc = 0; kc < KCH; ++kc){
        short8 av = *(const short8*)(ap + kc*32);
        short8 bv = *(const short8*)(bp + kc*32);
        acc = __builtin_amdgcn_mfma_f32_16x16x32_bf16(av, bv, acc, 0, 0, 0);
    }
    if (jt < 6 || col >= 96){
        int r0 = m16*16 + (lane >> 4)*4;
        #pragma unroll
        for (int r = 0; r < 4; ++r){
            int u = ihead[r0 + r];
            while (u >= 0){
                if (br == 0){
                    out[(size_t)u*100 + col] = acc[r];
                    out[(size_t)(UCNT + u)*100 + col] = acc[r];
                } else {
                    out[(size_t)(2*UCNT + u)*100 + col] = acc[r];
                }
                u = inext[u];
            }
        }
    }
}

extern "C" void kernel_launch(void* const* d_in, const int* in_sizes, int n_in,
                              void* d_out, int out_size, void* d_ws, size_t ws_size,
                              hipStream_t stream){
    const float* ent        = (const float*)d_in[0];
    const float* rel_table  = (const float*)d_in[1];
    const float* unseen_emb = (const float*)d_in[2];
    const float* att_mu     = (const float*)d_in[3];
    const float* basis_mu   = (const float*)d_in[4];
    const float* root_mu    = (const float*)d_in[5];
    const float* bias_mu    = (const float*)d_in[6];
    const float* att_sig    = (const float*)d_in[7];
    const float* basis_sig  = (const float*)d_in[8];
    const float* root_sig   = (const float*)d_in[9];
    const float* bias_sig   = (const float*)d_in[10];
    const int* node_id      = (const int*)d_in[11];
    const int* edge_index   = (const int*)d_in[12];
    const int* edge_type    = (const int*)d_in[13];
    const int* rel_index    = (const int*)d_in[14];
    const int* unseen_index = (const int*)d_in[15];
    float* out = (float*)d_out;
    char* ws = (char*)d_ws;

    int* ovr   = (int*)(ws + OFF_OVR);
    int* ihead = (int*)(ws + OFF_IHEA);
    int* inext = (int*)(ws + OFF_INEX);
    int* scnt  = (int*)(ws + OFF_SCNT);
    int* elist = (int*)(ws + OFF_EL2);
    unsigned short* Gm  = (unsigned short*)(ws + OFF_GM);
    unsigned short* Gs  = (unsigned short*)(ws + OFF_GS);
    unsigned short* Btm = (unsigned short*)(ws + OFF_BTM);
    unsigned short* Bts = (unsigned short*)(ws + OFF_BTS);

    k_setup<<<TR_BLOCKS + 1, 256, 0, stream>>>(unseen_index, ovr, ihead, inext, scnt,
        basis_mu, basis_sig, root_mu, root_sig, bias_mu, bias_sig, Btm, Bts);
    k_filter<<<(E2V/4 + 255)/256, 256, 0, stream>>>(edge_index, ovr, scnt, elist);
    k_g<<<MROWS, 256, 0, stream>>>(scnt, elist, ovr, edge_index, edge_type,
        rel_index, node_id, ent, unseen_emb, rel_table, att_mu, att_sig, Gm, Gs);
    k_gemm<<<112, 256, 0, stream>>>(Gm, Gs, Btm, Bts, ihead, inext, out);
}